// Round 13
// baseline (663.549 us; speedup 1.0000x reference)
//
#include <hip/hip_runtime.h>

#define EPS   0.01f
#define ALPHA 0.1f
#define H     60

typedef __attribute__((ext_vector_type(8))) short short8;
typedef __attribute__((ext_vector_type(4))) float float4v;
typedef __attribute__((ext_vector_type(4))) unsigned u32x4;
typedef __attribute__((ext_vector_type(2))) unsigned u32x2;

__device__ __forceinline__ float softplusf(float x) {
    float e = __expf(-fabsf(x));
    return fmaxf(x, 0.f) + __logf(1.f + e);
}
__device__ __forceinline__ unsigned bf16_rne(float x) {
    unsigned u = __builtin_bit_cast(unsigned, x);
    return (u + 0x7FFFu + ((u >> 16) & 1u)) >> 16;
}
__device__ __forceinline__ float bf16f(unsigned h) {
    return __builtin_bit_cast(float, h << 16);
}
__device__ __forceinline__ unsigned pack2bf(float a, float b) {
    return bf16_rne(a) | (bf16_rne(b) << 16);
}
__device__ __forceinline__ int kmap(int q, int j) { return q * 8 + j; }

// ws float layout:
// [0]=g0 | [16..272) kt float4[64]{w1a,w1b,b1,0} | [272..528) nt float4[64]{b2,wim2a,wim2b,w3}
// [528..2576) A1hi | [2576..4624) A1lo | [4624..6672) A2hi | [6672..8720) A2lo   (u32[2048] each)
#define WS_KT  16
#define WS_NT  272
#define WS_A1  528

__global__ void setup_kernel(const float* __restrict__ W1, const float* __restrict__ b1,
                             const float* __restrict__ W2, const float* __restrict__ b2,
                             const float* __restrict__ W3, const float* __restrict__ b3,
                             const float* __restrict__ Wim2, float* __restrict__ ws) {
    const int tid = threadIdx.x;
    float4*   kt  = (float4*)(ws + WS_KT);
    float4*   nt4 = (float4*)(ws + WS_NT);
    unsigned* A1hi = (unsigned*)(ws + WS_A1);
    unsigned* A1lo = A1hi + 2048;
    unsigned* A2hi = A1lo + 2048;
    unsigned* A2lo = A2hi + 2048;

    if (tid < 64) {
        float4 kv = make_float4(0.f, 0.f, 0.f, 0.f);
        float4 nv = make_float4(0.f, 0.f, 0.f, 0.f);
        if (tid < H) {
            kv.x = W1[2 * tid]; kv.y = W1[2 * tid + 1]; kv.z = b1[tid];
            nv.x = b2[tid]; nv.y = Wim2[2 * tid]; nv.z = Wim2[2 * tid + 1]; nv.w = W3[tid];
        }
        kt[tid] = kv; nt4[tid] = nv;
    }
    // A1 (GEMM1 A = W2):   value = W2[m][k]   (m = C-row = j, k over K)
    // A2 (GEMM2 A = W2^T): value = W2[k][m]   (m = C-row = k2, k = j)
    for (int idx = tid; idx < 2048; idx += 256) {
        const int frag = idx >> 2, rp = idx & 3;
        const int l = frag & 63, t2 = frag >> 6;
        const int kh = t2 & 1, tile = t2 >> 1;
        const int m  = tile * 16 + (l & 15);
        const int ka = kh * 32 + kmap(l >> 4, rp * 2);
        const int kb = kh * 32 + kmap(l >> 4, rp * 2 + 1);
        {
            float v0 = (ka < H && m < H) ? W2[m * H + ka] : 0.f;
            float v1 = (kb < H && m < H) ? W2[m * H + kb] : 0.f;
            unsigned h0 = bf16_rne(v0), h1 = bf16_rne(v1);
            A1hi[idx] = h0 | (h1 << 16);
            A1lo[idx] = bf16_rne(v0 - bf16f(h0)) | (bf16_rne(v1 - bf16f(h1)) << 16);
        }
        {
            float w0 = (ka < H && m < H) ? W2[ka * H + m] : 0.f;
            float w1 = (kb < H && m < H) ? W2[kb * H + m] : 0.f;
            unsigned h0 = bf16_rne(w0), h1 = bf16_rne(w1);
            A2hi[idx] = h0 | (h1 << 16);
            A2lo[idx] = bf16_rne(w0 - bf16f(h0)) | (bf16_rne(w1 - bf16f(h1)) << 16);
        }
    }
    if (tid == 0) {
        float h1v[H];
        for (int k = 0; k < H; ++k) h1v[k] = softplusf(b1[k]);
        float z3 = b3[0];
        for (int j = 0; j < H; ++j) {
            float acc = b2[j];
            for (int k = 0; k < H; ++k) acc = fmaf(W2[j * H + k], h1v[k], acc);
            z3 = fmaf(W3[j], softplusf(acc), z3);
        }
        ws[0] = softplusf(z3);
    }
}

// Swapped-operand fused kernel (r12 skeleton). Round-13: no persistent fragment
// registers (A loaded from ws per use, L1-cached) + launch_bounds(256,2) forces
// <=256 unified regs/wave -> 2 waves/SIMD. GEMM2 is now 3-pass split precision.
__global__ __launch_bounds__(256, 2) void fused_kernel(
    const float* __restrict__ X, const float* __restrict__ Wf,
    const float* __restrict__ Wim3, const float* __restrict__ b3,
    const float* __restrict__ ws, float* __restrict__ out, int B)
{
    __shared__ char Traw[4][2][2304];   // per-wave t-tiles (hi,lo): 16 rows x 144 B

    const int tid  = threadIdx.x;
    const int wid  = tid >> 6, lane = tid & 63;
    const int b    = lane & 15, qd = lane >> 4;
    const int rows0 = blockIdx.x * 256;

    const float g0  = ws[0];
    const float b3v = b3[0], wi30 = Wim3[0], wi31 = Wim3[1];
    const float wf0 = Wf[0], wf1 = Wf[1], wf2 = Wf[2], wf3 = Wf[3];

    const float4* ktT = (const float4*)(ws + WS_KT);
    const float4* ntT = (const float4*)(ws + WS_NT);
    const u32x4* A1hiT = (const u32x4*)(ws + WS_A1);
    const u32x4* A1loT = A1hiT + 512;
    const u32x4* A2hiT = A1loT + 512;
    const u32x4* A2loT = A2hiT + 512;

    char* Thi = &Traw[wid][0][0];
    char* Tlo = &Traw[wid][1][0];

    for (int blk = 0; blk < 4; ++blk) {
        const int rloc = wid * 64 + blk * 16;
        const int row  = rows0 + rloc + b;
        const float2 xv = ((const float2*)X)[row < B ? row : 0];
        const float x0 = xv.x, x1 = xv.y;

        // ---- B1 = h1 fragments (hi + residual-lo bf16) ----
        short8 B1hi[2], B1lo[2];
#pragma unroll
        for (int kh = 0; kh < 2; ++kh) {
#pragma unroll
            for (int e = 0; e < 8; ++e) {
                const int k = kh * 32 + 8 * qd + e;
                const float4 kv = ktT[k];
                const float z1 = fmaf(kv.x, x0, fmaf(kv.y, x1, kv.z));
                const float h1 = softplusf(z1);
                const unsigned hi = bf16_rne(h1);
                const unsigned lo = bf16_rne(h1 - bf16f(hi));
                B1hi[kh][e] = (short)hi;
                B1lo[kh][e] = (short)lo;
            }
        }

        // ---- GEMM1: z2[j][b], split-precision 3-pass; A from ws (L1) ----
        float4v acc[4];
#pragma unroll
        for (int jt = 0; jt < 4; ++jt) acc[jt] = (float4v){0.f, 0.f, 0.f, 0.f};
#pragma unroll
        for (int jt = 0; jt < 4; ++jt)
#pragma unroll
            for (int kh = 0; kh < 2; ++kh) {
                const int fi = (jt * 2 + kh) * 64 + lane;
                const short8 ahi = __builtin_bit_cast(short8, A1hiT[fi]);
                const short8 alo = __builtin_bit_cast(short8, A1loT[fi]);
                acc[jt] = __builtin_amdgcn_mfma_f32_16x16x32_bf16(ahi, B1hi[kh], acc[jt], 0, 0, 0);
                acc[jt] = __builtin_amdgcn_mfma_f32_16x16x32_bf16(alo, B1hi[kh], acc[jt], 0, 0, 0);
                acc[jt] = __builtin_amdgcn_mfma_f32_16x16x32_bf16(ahi, B1lo[kh], acc[jt], 0, 0, 0);
            }

        // ---- epilogue 1: per-lane over 16 j's; t -> hi/lo LDS tiles ----
        float z3p = 0.f, gi0p = 0.f, gi1p = 0.f;
#pragma unroll
        for (int jt = 0; jt < 4; ++jt) {
            float tv[4];
#pragma unroll
            for (int c = 0; c < 4; ++c) {
                const int j = jt * 16 + 4 * qd + c;
                const float4 nv = ntT[j];
                const float z2 = acc[jt][c] + fmaf(nv.y, x0, fmaf(nv.z, x1, nv.x));
                const float h2 = softplusf(z2);
                z3p = fmaf(nv.w, h2, z3p);
                const float tj = nv.w * (1.f - __expf(-h2));
                gi0p = fmaf(tj, nv.y, gi0p);
                gi1p = fmaf(tj, nv.z, gi1p);
                tv[c] = tj;
            }
            unsigned hw0 = bf16_rne(tv[0]), hw1 = bf16_rne(tv[1]);
            unsigned hw2 = bf16_rne(tv[2]), hw3 = bf16_rne(tv[3]);
            u32x2 thw, tlw;
            thw.x = hw0 | (hw1 << 16);
            thw.y = hw2 | (hw3 << 16);
            tlw.x = bf16_rne(tv[0] - bf16f(hw0)) | (bf16_rne(tv[1] - bf16f(hw1)) << 16);
            tlw.y = bf16_rne(tv[2] - bf16f(hw2)) | (bf16_rne(tv[3] - bf16f(hw3)) << 16);
            *(u32x2*)(Thi + b * 144 + jt * 32 + qd * 8) = thw;
            *(u32x2*)(Tlo + b * 144 + jt * 32 + qd * 8) = tlw;
        }

        // ---- B2 = t fragments from LDS ----
        short8 B2hi[2], B2lo[2];
#pragma unroll
        for (int kh = 0; kh < 2; ++kh) {
            B2hi[kh] = *(const short8*)(Thi + b * 144 + kh * 64 + qd * 16);
            B2lo[kh] = *(const short8*)(Tlo + b * 144 + kh * 64 + qd * 16);
        }

        // ---- GEMM2: G[k2][b], split-precision 3-pass; A from ws (L1) ----
        float4v gacc[4];
#pragma unroll
        for (int t = 0; t < 4; ++t) gacc[t] = (float4v){0.f, 0.f, 0.f, 0.f};
#pragma unroll
        for (int t = 0; t < 4; ++t)
#pragma unroll
            for (int kh = 0; kh < 2; ++kh) {
                const int fi = (t * 2 + kh) * 64 + lane;
                const short8 ahi = __builtin_bit_cast(short8, A2hiT[fi]);
                const short8 alo = __builtin_bit_cast(short8, A2loT[fi]);
                gacc[t] = __builtin_amdgcn_mfma_f32_16x16x32_bf16(ahi, B2hi[kh], gacc[t], 0, 0, 0);
                gacc[t] = __builtin_amdgcn_mfma_f32_16x16x32_bf16(alo, B2hi[kh], gacc[t], 0, 0, 0);
                gacc[t] = __builtin_amdgcn_mfma_f32_16x16x32_bf16(ahi, B2lo[kh], gacc[t], 0, 0, 0);
            }

        // ---- epilogue 2: per-lane over 16 k2's ----
        float q0p = 0.f, q1p = 0.f;
#pragma unroll
        for (int t = 0; t < 4; ++t)
#pragma unroll
            for (int c = 0; c < 4; ++c) {
                const int k2 = t * 16 + 4 * qd + c;
                const float4 kv = ktT[k2];
                const float z1 = fmaf(kv.x, x0, fmaf(kv.y, x1, kv.z));
                const float sg = __fdividef(1.f, 1.f + __expf(-z1));
                const float u1 = gacc[t][c] * sg;
                q0p = fmaf(u1, kv.x, q0p);
                q1p = fmaf(u1, kv.y, q1p);
            }

        // ---- qd-group reductions: 2 shuffle steps each ----
        z3p  += __shfl_xor(z3p, 16);  z3p  += __shfl_xor(z3p, 32);
        gi0p += __shfl_xor(gi0p, 16); gi0p += __shfl_xor(gi0p, 32);
        gi1p += __shfl_xor(gi1p, 16); gi1p += __shfl_xor(gi1p, 32);
        q0p  += __shfl_xor(q0p, 16);  q0p  += __shfl_xor(q0p, 32);
        q1p  += __shfl_xor(q1p, 16);  q1p  += __shfl_xor(q1p, 32);

        // ---- final per-row scalar math + store (qd==0 lanes) ----
        const float z3 = z3p + fmaf(wi30, x0, fmaf(wi31, x1, b3v));
        const float g  = softplusf(z3);
        const float u3 = (g > g0) ? (1.f - __expf(-g)) : 0.f;
        const float dv0 = fmaf(2.f * EPS, x0, u3 * (wi30 + gi0p + q0p));
        const float dv1 = fmaf(2.f * EPS, x1, u3 * (wi31 + gi1p + q1p));
        const float V  = fmaxf(g - g0, 0.f) + EPS * fmaf(x0, x0, x1 * x1);
        const float f0 = fmaf(wf0, x0, wf1 * x1);
        const float f1 = fmaf(wf2, x0, wf3 * x1);
        const float stab = fmaf(ALPHA, V, fmaf(dv0, f0, dv1 * f1));
        const float s = __fdividef(fmaxf(stab, 0.f), fmaf(dv0, dv0, dv1 * dv1));
        if (qd == 0 && row < B)
            ((float2*)out)[row] = make_float2(f0 - dv0 * s, f1 - dv1 * s);
    }
}

// ---- fallback (monolithic scalar) if ws is too small ----
__global__ void g0_kernel(const float* __restrict__ W2, const float* __restrict__ b1,
                          const float* __restrict__ b2, const float* __restrict__ W3,
                          const float* __restrict__ b3, float* __restrict__ g0_out) {
    if (threadIdx.x != 0 || blockIdx.x != 0) return;
    float h1[H];
    for (int k = 0; k < H; ++k) h1[k] = softplusf(b1[k]);
    float z3 = b3[0];
    for (int j = 0; j < H; ++j) {
        float acc = b2[j];
        for (int k = 0; k < H; ++k) acc = fmaf(W2[j * H + k], h1[k], acc);
        z3 = fmaf(W3[j], softplusf(acc), z3);
    }
    g0_out[0] = softplusf(z3);
}

__global__ __launch_bounds__(256) void sdnn_mono_kernel(
    const float* __restrict__ X,   const float* __restrict__ Wf,
    const float* __restrict__ W1,  const float* __restrict__ b1,
    const float* __restrict__ W2,  const float* __restrict__ b2,
    const float* __restrict__ W3,  const float* __restrict__ b3,
    const float* __restrict__ Wim2,const float* __restrict__ Wim3,
    const float* __restrict__ g0p, float* __restrict__ out, int B)
{
    const int row = blockIdx.x * 256 + threadIdx.x;
    if (row >= B) return;
    const float2 xv = ((const float2*)X)[row];
    const float x0 = xv.x, x1 = xv.y;
    float h1v[H];
#pragma unroll
    for (int k = 0; k < H; ++k)
        h1v[k] = softplusf(fmaf(W1[2 * k], x0, fmaf(W1[2 * k + 1], x1, b1[k])));
    float G[H];
#pragma unroll
    for (int k = 0; k < H; ++k) G[k] = 0.f;
    const float wi30 = Wim3[0], wi31 = Wim3[1];
    float z3 = fmaf(wi30, x0, fmaf(wi31, x1, b3[0]));
    float gim0 = 0.f, gim1 = 0.f;
    for (int j = 0; j < H; ++j) {
        const float* __restrict__ wrow = &W2[j * H];
        float a0 = 0.f, a1 = 0.f, a2 = 0.f, a3 = 0.f;
#pragma unroll
        for (int k = 0; k < H; k += 4) {
            a0 = fmaf(wrow[k + 0], h1v[k + 0], a0);
            a1 = fmaf(wrow[k + 1], h1v[k + 1], a1);
            a2 = fmaf(wrow[k + 2], h1v[k + 2], a2);
            a3 = fmaf(wrow[k + 3], h1v[k + 3], a3);
        }
        float acc = ((a0 + a1) + (a2 + a3))
                  + fmaf(Wim2[2 * j], x0, fmaf(Wim2[2 * j + 1], x1, b2[j]));
        const float h2  = softplusf(acc);
        const float w3j = W3[j];
        z3 = fmaf(w3j, h2, z3);
        const float tj = w3j * (1.f - __expf(-h2));
        gim0 = fmaf(tj, Wim2[2 * j],     gim0);
        gim1 = fmaf(tj, Wim2[2 * j + 1], gim1);
#pragma unroll
        for (int k = 0; k < H; ++k) G[k] = fmaf(wrow[k], tj, G[k]);
    }
    const float g0 = g0p[0];
    const float g  = softplusf(z3);
    const float u3 = (g > g0) ? (1.f - __expf(-g)) : 0.f;
    float q0 = 0.f, q1 = 0.f;
#pragma unroll
    for (int k = 0; k < H; ++k) {
        const float u1 = G[k] * (1.f - __expf(-h1v[k]));
        q0 = fmaf(u1, W1[2 * k],     q0);
        q1 = fmaf(u1, W1[2 * k + 1], q1);
    }
    const float dV0 = fmaf(2.f * EPS, x0, u3 * (wi30 + gim0 + q0));
    const float dV1 = fmaf(2.f * EPS, x1, u3 * (wi31 + gim1 + q1));
    const float V  = fmaxf(g - g0, 0.f) + EPS * fmaf(x0, x0, x1 * x1);
    const float f0 = fmaf(Wf[0], x0, Wf[1] * x1);
    const float f1 = fmaf(Wf[2], x0, Wf[3] * x1);
    const float stab = fmaf(ALPHA, V, fmaf(dV0, f0, dV1 * f1));
    const float s    = __fdividef(fmaxf(stab, 0.f), fmaf(dV0, dV0, dV1 * dV1));
    float2 o;
    o.x = f0 - dV0 * s;
    o.y = f1 - dV1 * s;
    ((float2*)out)[row] = o;
}

extern "C" void kernel_launch(void* const* d_in, const int* in_sizes, int n_in,
                              void* d_out, int out_size, void* d_ws, size_t ws_size,
                              hipStream_t stream) {
    const float* X    = (const float*)d_in[0];
    const float* Wf   = (const float*)d_in[1];
    const float* W1   = (const float*)d_in[2];
    const float* b1   = (const float*)d_in[3];
    const float* W2   = (const float*)d_in[4];
    const float* b2   = (const float*)d_in[5];
    const float* W3   = (const float*)d_in[6];
    const float* b3   = (const float*)d_in[7];
    const float* Wim2 = (const float*)d_in[8];
    const float* Wim3 = (const float*)d_in[9];
    float* out = (float*)d_out;
    float* wsf = (float*)d_ws;

    const int B = in_sizes[0] / 2;
    const int nwg = (B + 255) / 256;

    if (ws_size >= 8720u * 4u) {
        hipLaunchKernelGGL(setup_kernel, dim3(1), dim3(256), 0, stream,
                           W1, b1, W2, b2, W3, b3, Wim2, wsf);
        hipLaunchKernelGGL(fused_kernel, dim3(nwg), dim3(256), 0, stream,
                           X, Wf, Wim3, b3, wsf, out, B);
    } else {
        hipLaunchKernelGGL(g0_kernel, dim3(1), dim3(64), 0, stream,
                           W2, b1, b2, W3, b3, wsf);
        hipLaunchKernelGGL(sdnn_mono_kernel, dim3(nwg), dim3(256), 0, stream,
                           X, Wf, W1, b1, W2, b2, W3, b3, Wim2, Wim3, wsf, out, B);
    }
}

// Round 14
// 290.849 us; speedup vs baseline: 2.2814x; 2.2814x over previous
//
#include <hip/hip_runtime.h>

#define EPS   0.01f
#define ALPHA 0.1f
#define H     60

typedef __attribute__((ext_vector_type(8))) short short8;
typedef __attribute__((ext_vector_type(4))) float float4v;
typedef __attribute__((ext_vector_type(4))) unsigned u32x4;
typedef __attribute__((ext_vector_type(2))) unsigned u32x2;

__device__ __forceinline__ float softplusf(float x) {
    float e = __expf(-fabsf(x));
    return fmaxf(x, 0.f) + __logf(1.f + e);
}
__device__ __forceinline__ unsigned bf16_rne(float x) {
    unsigned u = __builtin_bit_cast(unsigned, x);
    return (u + 0x7FFFu + ((u >> 16) & 1u)) >> 16;
}
__device__ __forceinline__ float bf16f(unsigned h) {
    return __builtin_bit_cast(float, h << 16);
}
__device__ __forceinline__ int kmap(int q, int j) { return q * 8 + j; }

// ws float layout:
// [0]=g0 | [16..272) kt float4[64]{w1a,w1b,b1,0} | [272..528) nt float4[64]{b2,wim2a,wim2b,w3}
// [528..2576) A1hi | [2576..4624) A1lo | [4624..6672) A2hi | [6672..8720) A2lo   (u32[2048] each)
#define WS_KT  16
#define WS_NT  272
#define WS_A1  528

__global__ void setup_kernel(const float* __restrict__ W1, const float* __restrict__ b1,
                             const float* __restrict__ W2, const float* __restrict__ b2,
                             const float* __restrict__ W3, const float* __restrict__ b3,
                             const float* __restrict__ Wim2, float* __restrict__ ws) {
    const int tid = threadIdx.x;
    float4*   kt  = (float4*)(ws + WS_KT);
    float4*   nt4 = (float4*)(ws + WS_NT);
    unsigned* A1hi = (unsigned*)(ws + WS_A1);
    unsigned* A1lo = A1hi + 2048;
    unsigned* A2hi = A1lo + 2048;
    unsigned* A2lo = A2hi + 2048;

    if (tid < 64) {
        float4 kv = make_float4(0.f, 0.f, 0.f, 0.f);
        float4 nv = make_float4(0.f, 0.f, 0.f, 0.f);
        if (tid < H) {
            kv.x = W1[2 * tid]; kv.y = W1[2 * tid + 1]; kv.z = b1[tid];
            nv.x = b2[tid]; nv.y = Wim2[2 * tid]; nv.z = Wim2[2 * tid + 1]; nv.w = W3[tid];
        }
        kt[tid] = kv; nt4[tid] = nv;
    }
    // A1 (GEMM1 A = W2):   value = W2[m][k]   (m = C-row = j, k over K)
    // A2 (GEMM2 A = W2^T): value = W2[k][m]   (m = C-row = k2, k = j)
    for (int idx = tid; idx < 2048; idx += 256) {
        const int frag = idx >> 2, rp = idx & 3;
        const int l = frag & 63, t2 = frag >> 6;
        const int kh = t2 & 1, tile = t2 >> 1;
        const int m  = tile * 16 + (l & 15);
        const int ka = kh * 32 + kmap(l >> 4, rp * 2);
        const int kb = kh * 32 + kmap(l >> 4, rp * 2 + 1);
        {
            float v0 = (ka < H && m < H) ? W2[m * H + ka] : 0.f;
            float v1 = (kb < H && m < H) ? W2[m * H + kb] : 0.f;
            unsigned h0 = bf16_rne(v0), h1 = bf16_rne(v1);
            A1hi[idx] = h0 | (h1 << 16);
            A1lo[idx] = bf16_rne(v0 - bf16f(h0)) | (bf16_rne(v1 - bf16f(h1)) << 16);
        }
        {
            float w0 = (ka < H && m < H) ? W2[ka * H + m] : 0.f;
            float w1 = (kb < H && m < H) ? W2[kb * H + m] : 0.f;
            unsigned h0 = bf16_rne(w0), h1 = bf16_rne(w1);
            A2hi[idx] = h0 | (h1 << 16);
            A2lo[idx] = bf16_rne(w0 - bf16f(h0)) | (bf16_rne(w1 - bf16f(h1)) << 16);
        }
    }
    if (tid == 0) {
        float h1v[H];
        for (int k = 0; k < H; ++k) h1v[k] = softplusf(b1[k]);
        float z3 = b3[0];
        for (int j = 0; j < H; ++j) {
            float acc = b2[j];
            for (int k = 0; k < H; ++k) acc = fmaf(W2[j * H + k], h1v[k], acc);
            z3 = fmaf(W3[j], softplusf(acc), z3);
        }
        ws[0] = softplusf(z3);
    }
}

// Swapped-operand fused kernel (r12 skeleton). Round-14: fragment tables staged
// in LDS (32 KB/WG, one barrier), read per use via ds_read_b128 -> transient
// registers only (no 96-reg persistent fragments [r12 -> 1 wave/SIMD], no
// per-use global loads [r13 -> scratch spill storm]). Plain launch_bounds.
__global__ __launch_bounds__(256) void fused_kernel(
    const float* __restrict__ X, const float* __restrict__ Wf,
    const float* __restrict__ Wim3, const float* __restrict__ b3,
    const float* __restrict__ ws, float* __restrict__ out, int B)
{
    __shared__ unsigned sA1hi[2048], sA1lo[2048], sA2hi[2048], sA2lo[2048]; // 32 KB
    __shared__ char Traw[4][2][2304];   // per-wave t-tiles (hi,lo): 16 rows x 144 B

    const int tid  = threadIdx.x;
    const int wid  = tid >> 6, lane = tid & 63;
    const int b    = lane & 15, qd = lane >> 4;
    const int rows0 = blockIdx.x * 256;

    // ---- stage fragment tables global -> LDS (once) ----
    {
        const u32x4* gT = (const u32x4*)(ws + WS_A1);
        u32x4* s0 = (u32x4*)sA1hi; u32x4* s1 = (u32x4*)sA1lo;
        u32x4* s2 = (u32x4*)sA2hi; u32x4* s3 = (u32x4*)sA2lo;
        for (int i = tid; i < 512; i += 256) {
            s0[i] = gT[i];
            s1[i] = gT[512 + i];
            s2[i] = gT[1024 + i];
            s3[i] = gT[1536 + i];
        }
    }
    __syncthreads();

    const float g0  = ws[0];
    const float b3v = b3[0], wi30 = Wim3[0], wi31 = Wim3[1];
    const float wf0 = Wf[0], wf1 = Wf[1], wf2 = Wf[2], wf3 = Wf[3];

    const float4* ktT = (const float4*)(ws + WS_KT);
    const float4* ntT = (const float4*)(ws + WS_NT);

    char* Thi = &Traw[wid][0][0];
    char* Tlo = &Traw[wid][1][0];

    for (int blk = 0; blk < 4; ++blk) {
        const int rloc = wid * 64 + blk * 16;
        const int row  = rows0 + rloc + b;
        const float2 xv = ((const float2*)X)[row < B ? row : 0];
        const float x0 = xv.x, x1 = xv.y;

        // ---- B1 = h1 fragments (hi + residual-lo bf16) ----
        short8 B1hi[2], B1lo[2];
#pragma unroll
        for (int kh = 0; kh < 2; ++kh) {
#pragma unroll
            for (int e = 0; e < 8; ++e) {
                const int k = kh * 32 + 8 * qd + e;
                const float4 kv = ktT[k];
                const float z1 = fmaf(kv.x, x0, fmaf(kv.y, x1, kv.z));
                const float h1 = softplusf(z1);
                const unsigned hi = bf16_rne(h1);
                const unsigned lo = bf16_rne(h1 - bf16f(hi));
                B1hi[kh][e] = (short)hi;
                B1lo[kh][e] = (short)lo;
            }
        }

        // ---- GEMM1: z2[j][b], split-precision 3-pass; A from LDS ----
        float4v acc[4];
#pragma unroll
        for (int jt = 0; jt < 4; ++jt) acc[jt] = (float4v){0.f, 0.f, 0.f, 0.f};
#pragma unroll
        for (int jt = 0; jt < 4; ++jt)
#pragma unroll
            for (int kh = 0; kh < 2; ++kh) {
                const int fi = ((jt * 2 + kh) * 64 + lane) * 4;
                const short8 ahi = __builtin_bit_cast(short8, *(const u32x4*)&sA1hi[fi]);
                const short8 alo = __builtin_bit_cast(short8, *(const u32x4*)&sA1lo[fi]);
                acc[jt] = __builtin_amdgcn_mfma_f32_16x16x32_bf16(ahi, B1hi[kh], acc[jt], 0, 0, 0);
                acc[jt] = __builtin_amdgcn_mfma_f32_16x16x32_bf16(alo, B1hi[kh], acc[jt], 0, 0, 0);
                acc[jt] = __builtin_amdgcn_mfma_f32_16x16x32_bf16(ahi, B1lo[kh], acc[jt], 0, 0, 0);
            }

        // ---- epilogue 1: per-lane over 16 j's; t -> hi/lo LDS tiles ----
        float z3p = 0.f, gi0p = 0.f, gi1p = 0.f;
#pragma unroll
        for (int jt = 0; jt < 4; ++jt) {
            float tv[4];
#pragma unroll
            for (int c = 0; c < 4; ++c) {
                const int j = jt * 16 + 4 * qd + c;
                const float4 nv = ntT[j];
                const float z2 = acc[jt][c] + fmaf(nv.y, x0, fmaf(nv.z, x1, nv.x));
                const float h2 = softplusf(z2);
                z3p = fmaf(nv.w, h2, z3p);
                const float tj = nv.w * (1.f - __expf(-h2));
                gi0p = fmaf(tj, nv.y, gi0p);
                gi1p = fmaf(tj, nv.z, gi1p);
                tv[c] = tj;
            }
            unsigned hw0 = bf16_rne(tv[0]), hw1 = bf16_rne(tv[1]);
            unsigned hw2 = bf16_rne(tv[2]), hw3 = bf16_rne(tv[3]);
            u32x2 thw, tlw;
            thw.x = hw0 | (hw1 << 16);
            thw.y = hw2 | (hw3 << 16);
            tlw.x = bf16_rne(tv[0] - bf16f(hw0)) | (bf16_rne(tv[1] - bf16f(hw1)) << 16);
            tlw.y = bf16_rne(tv[2] - bf16f(hw2)) | (bf16_rne(tv[3] - bf16f(hw3)) << 16);
            *(u32x2*)(Thi + b * 144 + jt * 32 + qd * 8) = thw;
            *(u32x2*)(Tlo + b * 144 + jt * 32 + qd * 8) = tlw;
        }

        // ---- B2 = t fragments from LDS ----
        short8 B2hi[2], B2lo[2];
#pragma unroll
        for (int kh = 0; kh < 2; ++kh) {
            B2hi[kh] = *(const short8*)(Thi + b * 144 + kh * 64 + qd * 16);
            B2lo[kh] = *(const short8*)(Tlo + b * 144 + kh * 64 + qd * 16);
        }

        // ---- GEMM2: G[k2][b], split-precision 3-pass; A from LDS ----
        float4v gacc[4];
#pragma unroll
        for (int t = 0; t < 4; ++t) gacc[t] = (float4v){0.f, 0.f, 0.f, 0.f};
#pragma unroll
        for (int t = 0; t < 4; ++t)
#pragma unroll
            for (int kh = 0; kh < 2; ++kh) {
                const int fi = ((t * 2 + kh) * 64 + lane) * 4;
                const short8 ahi = __builtin_bit_cast(short8, *(const u32x4*)&sA2hi[fi]);
                const short8 alo = __builtin_bit_cast(short8, *(const u32x4*)&sA2lo[fi]);
                gacc[t] = __builtin_amdgcn_mfma_f32_16x16x32_bf16(ahi, B2hi[kh], gacc[t], 0, 0, 0);
                gacc[t] = __builtin_amdgcn_mfma_f32_16x16x32_bf16(alo, B2hi[kh], gacc[t], 0, 0, 0);
                gacc[t] = __builtin_amdgcn_mfma_f32_16x16x32_bf16(ahi, B2lo[kh], gacc[t], 0, 0, 0);
            }

        // ---- epilogue 2: per-lane over 16 k2's ----
        float q0p = 0.f, q1p = 0.f;
#pragma unroll
        for (int t = 0; t < 4; ++t)
#pragma unroll
            for (int c = 0; c < 4; ++c) {
                const int k2 = t * 16 + 4 * qd + c;
                const float4 kv = ktT[k2];
                const float z1 = fmaf(kv.x, x0, fmaf(kv.y, x1, kv.z));
                const float sg = __fdividef(1.f, 1.f + __expf(-z1));
                const float u1 = gacc[t][c] * sg;
                q0p = fmaf(u1, kv.x, q0p);
                q1p = fmaf(u1, kv.y, q1p);
            }

        // ---- qd-group reductions: 2 shuffle steps each ----
        z3p  += __shfl_xor(z3p, 16);  z3p  += __shfl_xor(z3p, 32);
        gi0p += __shfl_xor(gi0p, 16); gi0p += __shfl_xor(gi0p, 32);
        gi1p += __shfl_xor(gi1p, 16); gi1p += __shfl_xor(gi1p, 32);
        q0p  += __shfl_xor(q0p, 16);  q0p  += __shfl_xor(q0p, 32);
        q1p  += __shfl_xor(q1p, 16);  q1p  += __shfl_xor(q1p, 32);

        // ---- final per-row scalar math + store (qd==0 lanes) ----
        const float z3 = z3p + fmaf(wi30, x0, fmaf(wi31, x1, b3v));
        const float g  = softplusf(z3);
        const float u3 = (g > g0) ? (1.f - __expf(-g)) : 0.f;
        const float dv0 = fmaf(2.f * EPS, x0, u3 * (wi30 + gi0p + q0p));
        const float dv1 = fmaf(2.f * EPS, x1, u3 * (wi31 + gi1p + q1p));
        const float V  = fmaxf(g - g0, 0.f) + EPS * fmaf(x0, x0, x1 * x1);
        const float f0 = fmaf(wf0, x0, wf1 * x1);
        const float f1 = fmaf(wf2, x0, wf3 * x1);
        const float stab = fmaf(ALPHA, V, fmaf(dv0, f0, dv1 * f1));
        const float s = __fdividef(fmaxf(stab, 0.f), fmaf(dv0, dv0, dv1 * dv1));
        if (qd == 0 && row < B)
            ((float2*)out)[row] = make_float2(f0 - dv0 * s, f1 - dv1 * s);
    }
}

// ---- fallback (monolithic scalar) if ws is too small ----
__global__ void g0_kernel(const float* __restrict__ W2, const float* __restrict__ b1,
                          const float* __restrict__ b2, const float* __restrict__ W3,
                          const float* __restrict__ b3, float* __restrict__ g0_out) {
    if (threadIdx.x != 0 || blockIdx.x != 0) return;
    float h1[H];
    for (int k = 0; k < H; ++k) h1[k] = softplusf(b1[k]);
    float z3 = b3[0];
    for (int j = 0; j < H; ++j) {
        float acc = b2[j];
        for (int k = 0; k < H; ++k) acc = fmaf(W2[j * H + k], h1[k], acc);
        z3 = fmaf(W3[j], softplusf(acc), z3);
    }
    g0_out[0] = softplusf(z3);
}

__global__ __launch_bounds__(256) void sdnn_mono_kernel(
    const float* __restrict__ X,   const float* __restrict__ Wf,
    const float* __restrict__ W1,  const float* __restrict__ b1,
    const float* __restrict__ W2,  const float* __restrict__ b2,
    const float* __restrict__ W3,  const float* __restrict__ b3,
    const float* __restrict__ Wim2,const float* __restrict__ Wim3,
    const float* __restrict__ g0p, float* __restrict__ out, int B)
{
    const int row = blockIdx.x * 256 + threadIdx.x;
    if (row >= B) return;
    const float2 xv = ((const float2*)X)[row];
    const float x0 = xv.x, x1 = xv.y;
    float h1v[H];
#pragma unroll
    for (int k = 0; k < H; ++k)
        h1v[k] = softplusf(fmaf(W1[2 * k], x0, fmaf(W1[2 * k + 1], x1, b1[k])));
    float G[H];
#pragma unroll
    for (int k = 0; k < H; ++k) G[k] = 0.f;
    const float wi30 = Wim3[0], wi31 = Wim3[1];
    float z3 = fmaf(wi30, x0, fmaf(wi31, x1, b3[0]));
    float gim0 = 0.f, gim1 = 0.f;
    for (int j = 0; j < H; ++j) {
        const float* __restrict__ wrow = &W2[j * H];
        float a0 = 0.f, a1 = 0.f, a2 = 0.f, a3 = 0.f;
#pragma unroll
        for (int k = 0; k < H; k += 4) {
            a0 = fmaf(wrow[k + 0], h1v[k + 0], a0);
            a1 = fmaf(wrow[k + 1], h1v[k + 1], a1);
            a2 = fmaf(wrow[k + 2], h1v[k + 2], a2);
            a3 = fmaf(wrow[k + 3], h1v[k + 3], a3);
        }
        float acc = ((a0 + a1) + (a2 + a3))
                  + fmaf(Wim2[2 * j], x0, fmaf(Wim2[2 * j + 1], x1, b2[j]));
        const float h2  = softplusf(acc);
        const float w3j = W3[j];
        z3 = fmaf(w3j, h2, z3);
        const float tj = w3j * (1.f - __expf(-h2));
        gim0 = fmaf(tj, Wim2[2 * j],     gim0);
        gim1 = fmaf(tj, Wim2[2 * j + 1], gim1);
#pragma unroll
        for (int k = 0; k < H; ++k) G[k] = fmaf(wrow[k], tj, G[k]);
    }
    const float g0 = g0p[0];
    const float g  = softplusf(z3);
    const float u3 = (g > g0) ? (1.f - __expf(-g)) : 0.f;
    float q0 = 0.f, q1 = 0.f;
#pragma unroll
    for (int k = 0; k < H; ++k) {
        const float u1 = G[k] * (1.f - __expf(-h1v[k]));
        q0 = fmaf(u1, W1[2 * k],     q0);
        q1 = fmaf(u1, W1[2 * k + 1], q1);
    }
    const float dV0 = fmaf(2.f * EPS, x0, u3 * (wi30 + gim0 + q0));
    const float dV1 = fmaf(2.f * EPS, x1, u3 * (wi31 + gim1 + q1));
    const float V  = fmaxf(g - g0, 0.f) + EPS * fmaf(x0, x0, x1 * x1);
    const float f0 = fmaf(Wf[0], x0, Wf[1] * x1);
    const float f1 = fmaf(Wf[2], x0, Wf[3] * x1);
    const float stab = fmaf(ALPHA, V, fmaf(dV0, f0, dV1 * f1));
    const float s    = __fdividef(fmaxf(stab, 0.f), fmaf(dV0, dV0, dV1 * dV1));
    float2 o;
    o.x = f0 - dV0 * s;
    o.y = f1 - dV1 * s;
    ((float2*)out)[row] = o;
}

extern "C" void kernel_launch(void* const* d_in, const int* in_sizes, int n_in,
                              void* d_out, int out_size, void* d_ws, size_t ws_size,
                              hipStream_t stream) {
    const float* X    = (const float*)d_in[0];
    const float* Wf   = (const float*)d_in[1];
    const float* W1   = (const float*)d_in[2];
    const float* b1   = (const float*)d_in[3];
    const float* W2   = (const float*)d_in[4];
    const float* b2   = (const float*)d_in[5];
    const float* W3   = (const float*)d_in[6];
    const float* b3   = (const float*)d_in[7];
    const float* Wim2 = (const float*)d_in[8];
    const float* Wim3 = (const float*)d_in[9];
    float* out = (float*)d_out;
    float* wsf = (float*)d_ws;

    const int B = in_sizes[0] / 2;
    const int nwg = (B + 255) / 256;

    if (ws_size >= 8720u * 4u) {
        hipLaunchKernelGGL(setup_kernel, dim3(1), dim3(256), 0, stream,
                           W1, b1, W2, b2, W3, b3, Wim2, wsf);
        hipLaunchKernelGGL(fused_kernel, dim3(nwg), dim3(256), 0, stream,
                           X, Wf, Wim3, b3, wsf, out, B);
    } else {
        hipLaunchKernelGGL(g0_kernel, dim3(1), dim3(64), 0, stream,
                           W2, b1, b2, W3, b3, wsf);
        hipLaunchKernelGGL(sdnn_mono_kernel, dim3(nwg), dim3(256), 0, stream,
                           X, Wf, W1, b1, W2, b2, W3, b3, Wim2, Wim3, wsf, out, B);
    }
}

// Round 15
// 209.827 us; speedup vs baseline: 3.1624x; 1.3861x over previous
//
#include <hip/hip_runtime.h>

#define EPS   0.01f
#define ALPHA 0.1f
#define H     60

typedef __attribute__((ext_vector_type(8))) short short8;
typedef __attribute__((ext_vector_type(4))) float float4v;
typedef __attribute__((ext_vector_type(4))) unsigned u32x4;
typedef __attribute__((ext_vector_type(2))) unsigned u32x2;

__device__ __forceinline__ float softplusf(float x) {
    float e = __expf(-fabsf(x));
    return fmaxf(x, 0.f) + __logf(1.f + e);
}
__device__ __forceinline__ unsigned bf16_rne(float x) {
    unsigned u = __builtin_bit_cast(unsigned, x);
    return (u + 0x7FFFu + ((u >> 16) & 1u)) >> 16;
}
__device__ __forceinline__ float bf16f(unsigned h) {
    return __builtin_bit_cast(float, h << 16);
}
__device__ __forceinline__ int kmap(int q, int j) { return q * 8 + j; }

// ws float layout:
// [0]=g0 | [16..272) kt float4[64]{w1a,w1b,b1,0} | [272..528) nt float4[64]{b2,wim2a,wim2b,w3}
// [528..2576) A1hi | [2576..4624) A1lo | [4624..6672) A2hi | [6672..8720) A2lo   (u32[2048] each)
#define WS_KT  16
#define WS_NT  272
#define WS_A1  528

__global__ void setup_kernel(const float* __restrict__ W1, const float* __restrict__ b1,
                             const float* __restrict__ W2, const float* __restrict__ b2,
                             const float* __restrict__ W3, const float* __restrict__ b3,
                             const float* __restrict__ Wim2, float* __restrict__ ws) {
    const int tid = threadIdx.x;
    float4*   kt  = (float4*)(ws + WS_KT);
    float4*   nt4 = (float4*)(ws + WS_NT);
    unsigned* A1hi = (unsigned*)(ws + WS_A1);
    unsigned* A1lo = A1hi + 2048;
    unsigned* A2hi = A1lo + 2048;
    unsigned* A2lo = A2hi + 2048;

    if (tid < 64) {
        float4 kv = make_float4(0.f, 0.f, 0.f, 0.f);
        float4 nv = make_float4(0.f, 0.f, 0.f, 0.f);
        if (tid < H) {
            kv.x = W1[2 * tid]; kv.y = W1[2 * tid + 1]; kv.z = b1[tid];
            nv.x = b2[tid]; nv.y = Wim2[2 * tid]; nv.z = Wim2[2 * tid + 1]; nv.w = W3[tid];
        }
        kt[tid] = kv; nt4[tid] = nv;
    }
    // A1 (GEMM1 A = W2):   value = W2[m][k]   (m = C-row = j, k over K)
    // A2 (GEMM2 A = W2^T): value = W2[k][m]   (m = C-row = k2, k = j)
    for (int idx = tid; idx < 2048; idx += 256) {
        const int frag = idx >> 2, rp = idx & 3;
        const int l = frag & 63, t2 = frag >> 6;
        const int kh = t2 & 1, tile = t2 >> 1;
        const int m  = tile * 16 + (l & 15);
        const int ka = kh * 32 + kmap(l >> 4, rp * 2);
        const int kb = kh * 32 + kmap(l >> 4, rp * 2 + 1);
        {
            float v0 = (ka < H && m < H) ? W2[m * H + ka] : 0.f;
            float v1 = (kb < H && m < H) ? W2[m * H + kb] : 0.f;
            unsigned h0 = bf16_rne(v0), h1 = bf16_rne(v1);
            A1hi[idx] = h0 | (h1 << 16);
            A1lo[idx] = bf16_rne(v0 - bf16f(h0)) | (bf16_rne(v1 - bf16f(h1)) << 16);
        }
        {
            float w0 = (ka < H && m < H) ? W2[ka * H + m] : 0.f;
            float w1 = (kb < H && m < H) ? W2[kb * H + m] : 0.f;
            unsigned h0 = bf16_rne(w0), h1 = bf16_rne(w1);
            A2hi[idx] = h0 | (h1 << 16);
            A2lo[idx] = bf16_rne(w0 - bf16f(h0)) | (bf16_rne(w1 - bf16f(h1)) << 16);
        }
    }
    if (tid == 0) {
        float h1v[H];
        for (int k = 0; k < H; ++k) h1v[k] = softplusf(b1[k]);
        float z3 = b3[0];
        for (int j = 0; j < H; ++j) {
            float acc = b2[j];
            for (int k = 0; k < H; ++k) acc = fmaf(W2[j * H + k], h1v[k], acc);
            z3 = fmaf(W3[j], softplusf(acc), z3);
        }
        ws[0] = softplusf(z3);
    }
}

// Swapped-operand fused kernel. Round-15: r14 + anti-LICM memory clobber at the
// top of the blk loop. r12/r14 lesson: the compiler hoists ALL blk-invariant
// loads (LDS fragment tables AND ktT/ntT global tables, ~190 regs worth) ->
// VGPR 204 -> 1 wave/SIMD. The clobber forces per-iteration re-reads (L1/LDS
// hits, cheap) keeping registers transient -> 2-3 waves/SIMD.
__global__ __launch_bounds__(256) void fused_kernel(
    const float* __restrict__ X, const float* __restrict__ Wf,
    const float* __restrict__ Wim3, const float* __restrict__ b3,
    const float* __restrict__ ws, float* __restrict__ out, int B)
{
    __shared__ unsigned sA1hi[2048], sA1lo[2048], sA2hi[2048], sA2lo[2048]; // 32 KB
    __shared__ char Traw[4][2][2304];   // per-wave t-tiles (hi,lo): 16 rows x 144 B

    const int tid  = threadIdx.x;
    const int wid  = tid >> 6, lane = tid & 63;
    const int b    = lane & 15, qd = lane >> 4;
    const int rows0 = blockIdx.x * 256;

    // ---- stage fragment tables global -> LDS (once) ----
    {
        const u32x4* gT = (const u32x4*)(ws + WS_A1);
        u32x4* s0 = (u32x4*)sA1hi; u32x4* s1 = (u32x4*)sA1lo;
        u32x4* s2 = (u32x4*)sA2hi; u32x4* s3 = (u32x4*)sA2lo;
        for (int i = tid; i < 512; i += 256) {
            s0[i] = gT[i];
            s1[i] = gT[512 + i];
            s2[i] = gT[1024 + i];
            s3[i] = gT[1536 + i];
        }
    }
    __syncthreads();

    const float g0  = ws[0];
    const float b3v = b3[0], wi30 = Wim3[0], wi31 = Wim3[1];
    const float wf0 = Wf[0], wf1 = Wf[1], wf2 = Wf[2], wf3 = Wf[3];

    const float4* ktT = (const float4*)(ws + WS_KT);
    const float4* ntT = (const float4*)(ws + WS_NT);

    char* Thi = &Traw[wid][0][0];
    char* Tlo = &Traw[wid][1][0];

    for (int blk = 0; blk < 4; ++blk) {
        // Anti-LICM: forbid caching any table load across iterations.
        asm volatile("" ::: "memory");

        const int rloc = wid * 64 + blk * 16;
        const int row  = rows0 + rloc + b;
        const float2 xv = ((const float2*)X)[row < B ? row : 0];
        const float x0 = xv.x, x1 = xv.y;

        // ---- B1 = h1 fragments (hi + residual-lo bf16) ----
        short8 B1hi[2], B1lo[2];
#pragma unroll
        for (int kh = 0; kh < 2; ++kh) {
#pragma unroll
            for (int e = 0; e < 8; ++e) {
                const int k = kh * 32 + 8 * qd + e;
                const float4 kv = ktT[k];
                const float z1 = fmaf(kv.x, x0, fmaf(kv.y, x1, kv.z));
                const float h1 = softplusf(z1);
                const unsigned hi = bf16_rne(h1);
                const unsigned lo = bf16_rne(h1 - bf16f(hi));
                B1hi[kh][e] = (short)hi;
                B1lo[kh][e] = (short)lo;
            }
        }

        // ---- GEMM1: z2[j][b], split-precision 3-pass; A from LDS ----
        float4v acc[4];
#pragma unroll
        for (int jt = 0; jt < 4; ++jt) acc[jt] = (float4v){0.f, 0.f, 0.f, 0.f};
#pragma unroll
        for (int jt = 0; jt < 4; ++jt)
#pragma unroll
            for (int kh = 0; kh < 2; ++kh) {
                const int fi = ((jt * 2 + kh) * 64 + lane) * 4;
                const short8 ahi = __builtin_bit_cast(short8, *(const u32x4*)&sA1hi[fi]);
                const short8 alo = __builtin_bit_cast(short8, *(const u32x4*)&sA1lo[fi]);
                acc[jt] = __builtin_amdgcn_mfma_f32_16x16x32_bf16(ahi, B1hi[kh], acc[jt], 0, 0, 0);
                acc[jt] = __builtin_amdgcn_mfma_f32_16x16x32_bf16(alo, B1hi[kh], acc[jt], 0, 0, 0);
                acc[jt] = __builtin_amdgcn_mfma_f32_16x16x32_bf16(ahi, B1lo[kh], acc[jt], 0, 0, 0);
            }

        // ---- epilogue 1: per-lane over 16 j's; t -> hi/lo LDS tiles ----
        float z3p = 0.f, gi0p = 0.f, gi1p = 0.f;
#pragma unroll
        for (int jt = 0; jt < 4; ++jt) {
            float tv[4];
#pragma unroll
            for (int c = 0; c < 4; ++c) {
                const int j = jt * 16 + 4 * qd + c;
                const float4 nv = ntT[j];
                const float z2 = acc[jt][c] + fmaf(nv.y, x0, fmaf(nv.z, x1, nv.x));
                const float h2 = softplusf(z2);
                z3p = fmaf(nv.w, h2, z3p);
                const float tj = nv.w * (1.f - __expf(-h2));
                gi0p = fmaf(tj, nv.y, gi0p);
                gi1p = fmaf(tj, nv.z, gi1p);
                tv[c] = tj;
            }
            unsigned hw0 = bf16_rne(tv[0]), hw1 = bf16_rne(tv[1]);
            unsigned hw2 = bf16_rne(tv[2]), hw3 = bf16_rne(tv[3]);
            u32x2 thw, tlw;
            thw.x = hw0 | (hw1 << 16);
            thw.y = hw2 | (hw3 << 16);
            tlw.x = bf16_rne(tv[0] - bf16f(hw0)) | (bf16_rne(tv[1] - bf16f(hw1)) << 16);
            tlw.y = bf16_rne(tv[2] - bf16f(hw2)) | (bf16_rne(tv[3] - bf16f(hw3)) << 16);
            *(u32x2*)(Thi + b * 144 + jt * 32 + qd * 8) = thw;
            *(u32x2*)(Tlo + b * 144 + jt * 32 + qd * 8) = tlw;
        }

        // ---- B2 = t fragments from LDS ----
        short8 B2hi[2], B2lo[2];
#pragma unroll
        for (int kh = 0; kh < 2; ++kh) {
            B2hi[kh] = *(const short8*)(Thi + b * 144 + kh * 64 + qd * 16);
            B2lo[kh] = *(const short8*)(Tlo + b * 144 + kh * 64 + qd * 16);
        }

        // ---- GEMM2: G[k2][b], split-precision 3-pass; A from LDS ----
        float4v gacc[4];
#pragma unroll
        for (int t = 0; t < 4; ++t) gacc[t] = (float4v){0.f, 0.f, 0.f, 0.f};
#pragma unroll
        for (int t = 0; t < 4; ++t)
#pragma unroll
            for (int kh = 0; kh < 2; ++kh) {
                const int fi = ((t * 2 + kh) * 64 + lane) * 4;
                const short8 ahi = __builtin_bit_cast(short8, *(const u32x4*)&sA2hi[fi]);
                const short8 alo = __builtin_bit_cast(short8, *(const u32x4*)&sA2lo[fi]);
                gacc[t] = __builtin_amdgcn_mfma_f32_16x16x32_bf16(ahi, B2hi[kh], gacc[t], 0, 0, 0);
                gacc[t] = __builtin_amdgcn_mfma_f32_16x16x32_bf16(alo, B2hi[kh], gacc[t], 0, 0, 0);
                gacc[t] = __builtin_amdgcn_mfma_f32_16x16x32_bf16(ahi, B2lo[kh], gacc[t], 0, 0, 0);
            }

        // ---- epilogue 2: per-lane over 16 k2's ----
        float q0p = 0.f, q1p = 0.f;
#pragma unroll
        for (int t = 0; t < 4; ++t)
#pragma unroll
            for (int c = 0; c < 4; ++c) {
                const int k2 = t * 16 + 4 * qd + c;
                const float4 kv = ktT[k2];
                const float z1 = fmaf(kv.x, x0, fmaf(kv.y, x1, kv.z));
                const float sg = __fdividef(1.f, 1.f + __expf(-z1));
                const float u1 = gacc[t][c] * sg;
                q0p = fmaf(u1, kv.x, q0p);
                q1p = fmaf(u1, kv.y, q1p);
            }

        // ---- qd-group reductions: 2 shuffle steps each ----
        z3p  += __shfl_xor(z3p, 16);  z3p  += __shfl_xor(z3p, 32);
        gi0p += __shfl_xor(gi0p, 16); gi0p += __shfl_xor(gi0p, 32);
        gi1p += __shfl_xor(gi1p, 16); gi1p += __shfl_xor(gi1p, 32);
        q0p  += __shfl_xor(q0p, 16);  q0p  += __shfl_xor(q0p, 32);
        q1p  += __shfl_xor(q1p, 16);  q1p  += __shfl_xor(q1p, 32);

        // ---- final per-row scalar math + store (qd==0 lanes) ----
        const float z3 = z3p + fmaf(wi30, x0, fmaf(wi31, x1, b3v));
        const float g  = softplusf(z3);
        const float u3 = (g > g0) ? (1.f - __expf(-g)) : 0.f;
        const float dv0 = fmaf(2.f * EPS, x0, u3 * (wi30 + gi0p + q0p));
        const float dv1 = fmaf(2.f * EPS, x1, u3 * (wi31 + gi1p + q1p));
        const float V  = fmaxf(g - g0, 0.f) + EPS * fmaf(x0, x0, x1 * x1);
        const float f0 = fmaf(wf0, x0, wf1 * x1);
        const float f1 = fmaf(wf2, x0, wf3 * x1);
        const float stab = fmaf(ALPHA, V, fmaf(dv0, f0, dv1 * f1));
        const float s = __fdividef(fmaxf(stab, 0.f), fmaf(dv0, dv0, dv1 * dv1));
        if (qd == 0 && row < B)
            ((float2*)out)[row] = make_float2(f0 - dv0 * s, f1 - dv1 * s);
    }
}

// ---- fallback (monolithic scalar) if ws is too small ----
__global__ void g0_kernel(const float* __restrict__ W2, const float* __restrict__ b1,
                          const float* __restrict__ b2, const float* __restrict__ W3,
                          const float* __restrict__ b3, float* __restrict__ g0_out) {
    if (threadIdx.x != 0 || blockIdx.x != 0) return;
    float h1[H];
    for (int k = 0; k < H; ++k) h1[k] = softplusf(b1[k]);
    float z3 = b3[0];
    for (int j = 0; j < H; ++j) {
        float acc = b2[j];
        for (int k = 0; k < H; ++k) acc = fmaf(W2[j * H + k], h1[k], acc);
        z3 = fmaf(W3[j], softplusf(acc), z3);
    }
    g0_out[0] = softplusf(z3);
}

__global__ __launch_bounds__(256) void sdnn_mono_kernel(
    const float* __restrict__ X,   const float* __restrict__ Wf,
    const float* __restrict__ W1,  const float* __restrict__ b1,
    const float* __restrict__ W2,  const float* __restrict__ b2,
    const float* __restrict__ W3,  const float* __restrict__ b3,
    const float* __restrict__ Wim2,const float* __restrict__ Wim3,
    const float* __restrict__ g0p, float* __restrict__ out, int B)
{
    const int row = blockIdx.x * 256 + threadIdx.x;
    if (row >= B) return;
    const float2 xv = ((const float2*)X)[row];
    const float x0 = xv.x, x1 = xv.y;
    float h1v[H];
#pragma unroll
    for (int k = 0; k < H; ++k)
        h1v[k] = softplusf(fmaf(W1[2 * k], x0, fmaf(W1[2 * k + 1], x1, b1[k])));
    float G[H];
#pragma unroll
    for (int k = 0; k < H; ++k) G[k] = 0.f;
    const float wi30 = Wim3[0], wi31 = Wim3[1];
    float z3 = fmaf(wi30, x0, fmaf(wi31, x1, b3[0]));
    float gim0 = 0.f, gim1 = 0.f;
    for (int j = 0; j < H; ++j) {
        const float* __restrict__ wrow = &W2[j * H];
        float a0 = 0.f, a1 = 0.f, a2 = 0.f, a3 = 0.f;
#pragma unroll
        for (int k = 0; k < H; k += 4) {
            a0 = fmaf(wrow[k + 0], h1v[k + 0], a0);
            a1 = fmaf(wrow[k + 1], h1v[k + 1], a1);
            a2 = fmaf(wrow[k + 2], h1v[k + 2], a2);
            a3 = fmaf(wrow[k + 3], h1v[k + 3], a3);
        }
        float acc = ((a0 + a1) + (a2 + a3))
                  + fmaf(Wim2[2 * j], x0, fmaf(Wim2[2 * j + 1], x1, b2[j]));
        const float h2  = softplusf(acc);
        const float w3j = W3[j];
        z3 = fmaf(w3j, h2, z3);
        const float tj = w3j * (1.f - __expf(-h2));
        gim0 = fmaf(tj, Wim2[2 * j],     gim0);
        gim1 = fmaf(tj, Wim2[2 * j + 1], gim1);
#pragma unroll
        for (int k = 0; k < H; ++k) G[k] = fmaf(wrow[k], tj, G[k]);
    }
    const float g0 = g0p[0];
    const float g  = softplusf(z3);
    const float u3 = (g > g0) ? (1.f - __expf(-g)) : 0.f;
    float q0 = 0.f, q1 = 0.f;
#pragma unroll
    for (int k = 0; k < H; ++k) {
        const float u1 = G[k] * (1.f - __expf(-h1v[k]));
        q0 = fmaf(u1, W1[2 * k],     q0);
        q1 = fmaf(u1, W1[2 * k + 1], q1);
    }
    const float dV0 = fmaf(2.f * EPS, x0, u3 * (wi30 + gim0 + q0));
    const float dV1 = fmaf(2.f * EPS, x1, u3 * (wi31 + gim1 + q1));
    const float V  = fmaxf(g - g0, 0.f) + EPS * fmaf(x0, x0, x1 * x1);
    const float f0 = fmaf(Wf[0], x0, Wf[1] * x1);
    const float f1 = fmaf(Wf[2], x0, Wf[3] * x1);
    const float stab = fmaf(ALPHA, V, fmaf(dV0, f0, dV1 * f1));
    const float s    = __fdividef(fmaxf(stab, 0.f), fmaf(dV0, dV0, dV1 * dV1));
    float2 o;
    o.x = f0 - dV0 * s;
    o.y = f1 - dV1 * s;
    ((float2*)out)[row] = o;
}

extern "C" void kernel_launch(void* const* d_in, const int* in_sizes, int n_in,
                              void* d_out, int out_size, void* d_ws, size_t ws_size,
                              hipStream_t stream) {
    const float* X    = (const float*)d_in[0];
    const float* Wf   = (const float*)d_in[1];
    const float* W1   = (const float*)d_in[2];
    const float* b1   = (const float*)d_in[3];
    const float* W2   = (const float*)d_in[4];
    const float* b2   = (const float*)d_in[5];
    const float* W3   = (const float*)d_in[6];
    const float* b3   = (const float*)d_in[7];
    const float* Wim2 = (const float*)d_in[8];
    const float* Wim3 = (const float*)d_in[9];
    float* out = (float*)d_out;
    float* wsf = (float*)d_ws;

    const int B = in_sizes[0] / 2;
    const int nwg = (B + 255) / 256;

    if (ws_size >= 8720u * 4u) {
        hipLaunchKernelGGL(setup_kernel, dim3(1), dim3(256), 0, stream,
                           W1, b1, W2, b2, W3, b3, Wim2, wsf);
        hipLaunchKernelGGL(fused_kernel, dim3(nwg), dim3(256), 0, stream,
                           X, Wf, Wim3, b3, wsf, out, B);
    } else {
        hipLaunchKernelGGL(g0_kernel, dim3(1), dim3(64), 0, stream,
                           W2, b1, b2, W3, b3, wsf);
        hipLaunchKernelGGL(sdnn_mono_kernel, dim3(nwg), dim3(256), 0, stream,
                           X, Wf, W1, b1, W2, b2, W3, b3, Wim2, Wim3, wsf, out, B);
    }
}

// Round 16
// 209.089 us; speedup vs baseline: 3.1735x; 1.0035x over previous
//
#include <hip/hip_runtime.h>

#define EPS   0.01f
#define ALPHA 0.1f
#define H     60

typedef __attribute__((ext_vector_type(8))) short short8;
typedef __attribute__((ext_vector_type(4))) float float4v;
typedef __attribute__((ext_vector_type(4))) unsigned u32x4;
typedef __attribute__((ext_vector_type(2))) unsigned u32x2;

__device__ __forceinline__ float softplusf(float x) {
    float e = __expf(-fabsf(x));
    return fmaxf(x, 0.f) + __logf(1.f + e);
}
__device__ __forceinline__ unsigned bf16_rne(float x) {
    unsigned u = __builtin_bit_cast(unsigned, x);
    return (u + 0x7FFFu + ((u >> 16) & 1u)) >> 16;
}
__device__ __forceinline__ float bf16f(unsigned h) {
    return __builtin_bit_cast(float, h << 16);
}
__device__ __forceinline__ int kmap(int q, int j) { return q * 8 + j; }

// ws float layout:
// [0]=g0 | [16..272) kt float4[64]{w1a,w1b,b1,0} | [272..528) nt float4[64]{b2,wim2a,wim2b,w3}
// [528..2576) A1hi | [2576..4624) A1lo | [4624..6672) A2hi | [6672..8720) A2lo   (u32[2048] each)
#define WS_KT  16
#define WS_NT  272
#define WS_A1  528

__global__ void setup_kernel(const float* __restrict__ W1, const float* __restrict__ b1,
                             const float* __restrict__ W2, const float* __restrict__ b2,
                             const float* __restrict__ W3, const float* __restrict__ b3,
                             const float* __restrict__ Wim2, float* __restrict__ ws) {
    const int tid = threadIdx.x;
    float4*   kt  = (float4*)(ws + WS_KT);
    float4*   nt4 = (float4*)(ws + WS_NT);
    unsigned* A1hi = (unsigned*)(ws + WS_A1);
    unsigned* A1lo = A1hi + 2048;
    unsigned* A2hi = A1lo + 2048;
    unsigned* A2lo = A2hi + 2048;

    if (tid < 64) {
        float4 kv = make_float4(0.f, 0.f, 0.f, 0.f);
        float4 nv = make_float4(0.f, 0.f, 0.f, 0.f);
        if (tid < H) {
            kv.x = W1[2 * tid]; kv.y = W1[2 * tid + 1]; kv.z = b1[tid];
            nv.x = b2[tid]; nv.y = Wim2[2 * tid]; nv.z = Wim2[2 * tid + 1]; nv.w = W3[tid];
        }
        kt[tid] = kv; nt4[tid] = nv;
    }
    // A1 (GEMM1 A = W2):   value = W2[m][k]   (m = C-row = j, k over K)
    // A2 (GEMM2 A = W2^T): value = W2[k][m]   (m = C-row = k2, k = j)
    for (int idx = tid; idx < 2048; idx += 256) {
        const int frag = idx >> 2, rp = idx & 3;
        const int l = frag & 63, t2 = frag >> 6;
        const int kh = t2 & 1, tile = t2 >> 1;
        const int m  = tile * 16 + (l & 15);
        const int ka = kh * 32 + kmap(l >> 4, rp * 2);
        const int kb = kh * 32 + kmap(l >> 4, rp * 2 + 1);
        {
            float v0 = (ka < H && m < H) ? W2[m * H + ka] : 0.f;
            float v1 = (kb < H && m < H) ? W2[m * H + kb] : 0.f;
            unsigned h0 = bf16_rne(v0), h1 = bf16_rne(v1);
            A1hi[idx] = h0 | (h1 << 16);
            A1lo[idx] = bf16_rne(v0 - bf16f(h0)) | (bf16_rne(v1 - bf16f(h1)) << 16);
        }
        {
            float w0 = (ka < H && m < H) ? W2[ka * H + m] : 0.f;
            float w1 = (kb < H && m < H) ? W2[kb * H + m] : 0.f;
            unsigned h0 = bf16_rne(w0), h1 = bf16_rne(w1);
            A2hi[idx] = h0 | (h1 << 16);
            A2lo[idx] = bf16_rne(w0 - bf16f(h0)) | (bf16_rne(w1 - bf16f(h1)) << 16);
        }
    }
    if (tid == 0) {
        float h1v[H];
        for (int k = 0; k < H; ++k) h1v[k] = softplusf(b1[k]);
        float z3 = b3[0];
        for (int j = 0; j < H; ++j) {
            float acc = b2[j];
            for (int k = 0; k < H; ++k) acc = fmaf(W2[j * H + k], h1v[k], acc);
            z3 = fmaf(W3[j], softplusf(acc), z3);
        }
        ws[0] = softplusf(z3);
    }
}

// Swapped-operand fused kernel. Round-16 = r15 + (a) kt/nt tables in LDS (all
// in-loop table reads are now ds_read, not global L1 hits) + (b) GEMM2 drops
// the t-residual pass (B2lo) and its Tlo tile — r4 evidence: t-bf16 with
// accurate W2^T costs ~0.004 absmax. A2lo (W2-correction) pass retained.
__global__ __launch_bounds__(256) void fused_kernel(
    const float* __restrict__ X, const float* __restrict__ Wf,
    const float* __restrict__ Wim3, const float* __restrict__ b3,
    const float* __restrict__ ws, float* __restrict__ out, int B)
{
    __shared__ unsigned sA1hi[2048], sA1lo[2048], sA2hi[2048], sA2lo[2048]; // 32 KB
    __shared__ float4 sKT[64], sNT[64];                                     // 2 KB
    __shared__ char Traw[4][2304];   // per-wave t-tile (hi only): 16 rows x 144 B

    const int tid  = threadIdx.x;
    const int wid  = tid >> 6, lane = tid & 63;
    const int b    = lane & 15, qd = lane >> 4;
    const int rows0 = blockIdx.x * 256;

    // ---- stage tables global -> LDS (once) ----
    {
        const u32x4* gT = (const u32x4*)(ws + WS_A1);
        u32x4* s0 = (u32x4*)sA1hi; u32x4* s1 = (u32x4*)sA1lo;
        u32x4* s2 = (u32x4*)sA2hi; u32x4* s3 = (u32x4*)sA2lo;
        for (int i = tid; i < 512; i += 256) {
            s0[i] = gT[i];
            s1[i] = gT[512 + i];
            s2[i] = gT[1024 + i];
            s3[i] = gT[1536 + i];
        }
        if (tid < 64) {
            sKT[tid] = ((const float4*)(ws + WS_KT))[tid];
            sNT[tid] = ((const float4*)(ws + WS_NT))[tid];
        }
    }
    __syncthreads();

    const float g0  = ws[0];
    const float b3v = b3[0], wi30 = Wim3[0], wi31 = Wim3[1];
    const float wf0 = Wf[0], wf1 = Wf[1], wf2 = Wf[2], wf3 = Wf[3];

    char* Thi = &Traw[wid][0];

    for (int blk = 0; blk < 4; ++blk) {
        // Anti-LICM: forbid caching any table load across iterations (r14
        // lesson: LICM caches ~190 regs of tables -> 1 wave/SIMD).
        asm volatile("" ::: "memory");

        const int rloc = wid * 64 + blk * 16;
        const int row  = rows0 + rloc + b;
        const float2 xv = ((const float2*)X)[row < B ? row : 0];
        const float x0 = xv.x, x1 = xv.y;

        // ---- B1 = h1 fragments (hi + residual-lo bf16) ----
        short8 B1hi[2], B1lo[2];
#pragma unroll
        for (int kh = 0; kh < 2; ++kh) {
#pragma unroll
            for (int e = 0; e < 8; ++e) {
                const int k = kh * 32 + 8 * qd + e;
                const float4 kv = sKT[k];
                const float z1 = fmaf(kv.x, x0, fmaf(kv.y, x1, kv.z));
                const float h1 = softplusf(z1);
                const unsigned hi = bf16_rne(h1);
                const unsigned lo = bf16_rne(h1 - bf16f(hi));
                B1hi[kh][e] = (short)hi;
                B1lo[kh][e] = (short)lo;
            }
        }

        // ---- GEMM1: z2[j][b], split-precision 3-pass; A from LDS ----
        float4v acc[4];
#pragma unroll
        for (int jt = 0; jt < 4; ++jt) acc[jt] = (float4v){0.f, 0.f, 0.f, 0.f};
#pragma unroll
        for (int jt = 0; jt < 4; ++jt)
#pragma unroll
            for (int kh = 0; kh < 2; ++kh) {
                const int fi = ((jt * 2 + kh) * 64 + lane) * 4;
                const short8 ahi = __builtin_bit_cast(short8, *(const u32x4*)&sA1hi[fi]);
                const short8 alo = __builtin_bit_cast(short8, *(const u32x4*)&sA1lo[fi]);
                acc[jt] = __builtin_amdgcn_mfma_f32_16x16x32_bf16(ahi, B1hi[kh], acc[jt], 0, 0, 0);
                acc[jt] = __builtin_amdgcn_mfma_f32_16x16x32_bf16(alo, B1hi[kh], acc[jt], 0, 0, 0);
                acc[jt] = __builtin_amdgcn_mfma_f32_16x16x32_bf16(ahi, B1lo[kh], acc[jt], 0, 0, 0);
            }

        // ---- epilogue 1: per-lane over 16 j's; t(hi only) -> LDS tile ----
        float z3p = 0.f, gi0p = 0.f, gi1p = 0.f;
#pragma unroll
        for (int jt = 0; jt < 4; ++jt) {
            float tv[4];
#pragma unroll
            for (int c = 0; c < 4; ++c) {
                const int j = jt * 16 + 4 * qd + c;
                const float4 nv = sNT[j];
                const float z2 = acc[jt][c] + fmaf(nv.y, x0, fmaf(nv.z, x1, nv.x));
                const float h2 = softplusf(z2);
                z3p = fmaf(nv.w, h2, z3p);
                const float tj = nv.w * (1.f - __expf(-h2));
                gi0p = fmaf(tj, nv.y, gi0p);
                gi1p = fmaf(tj, nv.z, gi1p);
                tv[c] = tj;
            }
            u32x2 thw;
            thw.x = bf16_rne(tv[0]) | (bf16_rne(tv[1]) << 16);
            thw.y = bf16_rne(tv[2]) | (bf16_rne(tv[3]) << 16);
            *(u32x2*)(Thi + b * 144 + jt * 32 + qd * 8) = thw;
        }

        // ---- B2 = t fragments from LDS ----
        short8 B2hi[2];
#pragma unroll
        for (int kh = 0; kh < 2; ++kh)
            B2hi[kh] = *(const short8*)(Thi + b * 144 + kh * 64 + qd * 16);

        // ---- GEMM2: G[k2][b], 2-pass (A2hi+A2lo) x t-hi; A from LDS ----
        float4v gacc[4];
#pragma unroll
        for (int t = 0; t < 4; ++t) gacc[t] = (float4v){0.f, 0.f, 0.f, 0.f};
#pragma unroll
        for (int t = 0; t < 4; ++t)
#pragma unroll
            for (int kh = 0; kh < 2; ++kh) {
                const int fi = ((t * 2 + kh) * 64 + lane) * 4;
                const short8 ahi = __builtin_bit_cast(short8, *(const u32x4*)&sA2hi[fi]);
                const short8 alo = __builtin_bit_cast(short8, *(const u32x4*)&sA2lo[fi]);
                gacc[t] = __builtin_amdgcn_mfma_f32_16x16x32_bf16(ahi, B2hi[kh], gacc[t], 0, 0, 0);
                gacc[t] = __builtin_amdgcn_mfma_f32_16x16x32_bf16(alo, B2hi[kh], gacc[t], 0, 0, 0);
            }

        // ---- epilogue 2: per-lane over 16 k2's ----
        float q0p = 0.f, q1p = 0.f;
#pragma unroll
        for (int t = 0; t < 4; ++t)
#pragma unroll
            for (int c = 0; c < 4; ++c) {
                const int k2 = t * 16 + 4 * qd + c;
                const float4 kv = sKT[k2];
                const float z1 = fmaf(kv.x, x0, fmaf(kv.y, x1, kv.z));
                const float sg = __fdividef(1.f, 1.f + __expf(-z1));
                const float u1 = gacc[t][c] * sg;
                q0p = fmaf(u1, kv.x, q0p);
                q1p = fmaf(u1, kv.y, q1p);
            }

        // ---- qd-group reductions: 2 shuffle steps each ----
        z3p  += __shfl_xor(z3p, 16);  z3p  += __shfl_xor(z3p, 32);
        gi0p += __shfl_xor(gi0p, 16); gi0p += __shfl_xor(gi0p, 32);
        gi1p += __shfl_xor(gi1p, 16); gi1p += __shfl_xor(gi1p, 32);
        q0p  += __shfl_xor(q0p, 16);  q0p  += __shfl_xor(q0p, 32);
        q1p  += __shfl_xor(q1p, 16);  q1p  += __shfl_xor(q1p, 32);

        // ---- final per-row scalar math + store (qd==0 lanes) ----
        const float z3 = z3p + fmaf(wi30, x0, fmaf(wi31, x1, b3v));
        const float g  = softplusf(z3);
        const float u3 = (g > g0) ? (1.f - __expf(-g)) : 0.f;
        const float dv0 = fmaf(2.f * EPS, x0, u3 * (wi30 + gi0p + q0p));
        const float dv1 = fmaf(2.f * EPS, x1, u3 * (wi31 + gi1p + q1p));
        const float V  = fmaxf(g - g0, 0.f) + EPS * fmaf(x0, x0, x1 * x1);
        const float f0 = fmaf(wf0, x0, wf1 * x1);
        const float f1 = fmaf(wf2, x0, wf3 * x1);
        const float stab = fmaf(ALPHA, V, fmaf(dv0, f0, dv1 * f1));
        const float s = __fdividef(fmaxf(stab, 0.f), fmaf(dv0, dv0, dv1 * dv1));
        if (qd == 0 && row < B)
            ((float2*)out)[row] = make_float2(f0 - dv0 * s, f1 - dv1 * s);
    }
}

// ---- fallback (monolithic scalar) if ws is too small ----
__global__ void g0_kernel(const float* __restrict__ W2, const float* __restrict__ b1,
                          const float* __restrict__ b2, const float* __restrict__ W3,
                          const float* __restrict__ b3, float* __restrict__ g0_out) {
    if (threadIdx.x != 0 || blockIdx.x != 0) return;
    float h1[H];
    for (int k = 0; k < H; ++k) h1[k] = softplusf(b1[k]);
    float z3 = b3[0];
    for (int j = 0; j < H; ++j) {
        float acc = b2[j];
        for (int k = 0; k < H; ++k) acc = fmaf(W2[j * H + k], h1[k], acc);
        z3 = fmaf(W3[j], softplusf(acc), z3);
    }
    g0_out[0] = softplusf(z3);
}

__global__ __launch_bounds__(256) void sdnn_mono_kernel(
    const float* __restrict__ X,   const float* __restrict__ Wf,
    const float* __restrict__ W1,  const float* __restrict__ b1,
    const float* __restrict__ W2,  const float* __restrict__ b2,
    const float* __restrict__ W3,  const float* __restrict__ b3,
    const float* __restrict__ Wim2,const float* __restrict__ Wim3,
    const float* __restrict__ g0p, float* __restrict__ out, int B)
{
    const int row = blockIdx.x * 256 + threadIdx.x;
    if (row >= B) return;
    const float2 xv = ((const float2*)X)[row];
    const float x0 = xv.x, x1 = xv.y;
    float h1v[H];
#pragma unroll
    for (int k = 0; k < H; ++k)
        h1v[k] = softplusf(fmaf(W1[2 * k], x0, fmaf(W1[2 * k + 1], x1, b1[k])));
    float G[H];
#pragma unroll
    for (int k = 0; k < H; ++k) G[k] = 0.f;
    const float wi30 = Wim3[0], wi31 = Wim3[1];
    float z3 = fmaf(wi30, x0, fmaf(wi31, x1, b3[0]));
    float gim0 = 0.f, gim1 = 0.f;
    for (int j = 0; j < H; ++j) {
        const float* __restrict__ wrow = &W2[j * H];
        float a0 = 0.f, a1 = 0.f, a2 = 0.f, a3 = 0.f;
#pragma unroll
        for (int k = 0; k < H; k += 4) {
            a0 = fmaf(wrow[k + 0], h1v[k + 0], a0);
            a1 = fmaf(wrow[k + 1], h1v[k + 1], a1);
            a2 = fmaf(wrow[k + 2], h1v[k + 2], a2);
            a3 = fmaf(wrow[k + 3], h1v[k + 3], a3);
        }
        float acc = ((a0 + a1) + (a2 + a3))
                  + fmaf(Wim2[2 * j], x0, fmaf(Wim2[2 * j + 1], x1, b2[j]));
        const float h2  = softplusf(acc);
        const float w3j = W3[j];
        z3 = fmaf(w3j, h2, z3);
        const float tj = w3j * (1.f - __expf(-h2));
        gim0 = fmaf(tj, Wim2[2 * j],     gim0);
        gim1 = fmaf(tj, Wim2[2 * j + 1], gim1);
#pragma unroll
        for (int k = 0; k < H; ++k) G[k] = fmaf(wrow[k], tj, G[k]);
    }
    const float g0 = g0p[0];
    const float g  = softplusf(z3);
    const float u3 = (g > g0) ? (1.f - __expf(-g)) : 0.f;
    float q0 = 0.f, q1 = 0.f;
#pragma unroll
    for (int k = 0; k < H; ++k) {
        const float u1 = G[k] * (1.f - __expf(-h1v[k]));
        q0 = fmaf(u1, W1[2 * k],     q0);
        q1 = fmaf(u1, W1[2 * k + 1], q1);
    }
    const float dV0 = fmaf(2.f * EPS, x0, u3 * (wi30 + gim0 + q0));
    const float dV1 = fmaf(2.f * EPS, x1, u3 * (wi31 + gim1 + q1));
    const float V  = fmaxf(g - g0, 0.f) + EPS * fmaf(x0, x0, x1 * x1);
    const float f0 = fmaf(Wf[0], x0, Wf[1] * x1);
    const float f1 = fmaf(Wf[2], x0, Wf[3] * x1);
    const float stab = fmaf(ALPHA, V, fmaf(dV0, f0, dV1 * f1));
    const float s    = __fdividef(fmaxf(stab, 0.f), fmaf(dV0, dV0, dV1 * dV1));
    float2 o;
    o.x = f0 - dV0 * s;
    o.y = f1 - dV1 * s;
    ((float2*)out)[row] = o;
}

extern "C" void kernel_launch(void* const* d_in, const int* in_sizes, int n_in,
                              void* d_out, int out_size, void* d_ws, size_t ws_size,
                              hipStream_t stream) {
    const float* X    = (const float*)d_in[0];
    const float* Wf   = (const float*)d_in[1];
    const float* W1   = (const float*)d_in[2];
    const float* b1   = (const float*)d_in[3];
    const float* W2   = (const float*)d_in[4];
    const float* b2   = (const float*)d_in[5];
    const float* W3   = (const float*)d_in[6];
    const float* b3   = (const float*)d_in[7];
    const float* Wim2 = (const float*)d_in[8];
    const float* Wim3 = (const float*)d_in[9];
    float* out = (float*)d_out;
    float* wsf = (float*)d_ws;

    const int B = in_sizes[0] / 2;
    const int nwg = (B + 255) / 256;

    if (ws_size >= 8720u * 4u) {
        hipLaunchKernelGGL(setup_kernel, dim3(1), dim3(256), 0, stream,
                           W1, b1, W2, b2, W3, b3, Wim2, wsf);
        hipLaunchKernelGGL(fused_kernel, dim3(nwg), dim3(256), 0, stream,
                           X, Wf, Wim3, b3, wsf, out, B);
    } else {
        hipLaunchKernelGGL(g0_kernel, dim3(1), dim3(64), 0, stream,
                           W2, b1, b2, W3, b3, wsf);
        hipLaunchKernelGGL(sdnn_mono_kernel, dim3(nwg), dim3(256), 0, stream,
                           X, Wf, W1, b1, W2, b2, W3, b3, Wim2, Wim3, wsf, out, B);
    }
}

// Round 17
// 200.746 us; speedup vs baseline: 3.3054x; 1.0416x over previous
//
#include <hip/hip_runtime.h>

#define EPS   0.01f
#define ALPHA 0.1f
#define H     60

typedef __attribute__((ext_vector_type(8))) short short8;
typedef __attribute__((ext_vector_type(4))) float float4v;
typedef __attribute__((ext_vector_type(4))) unsigned u32x4;
typedef __attribute__((ext_vector_type(2))) unsigned u32x2;

__device__ __forceinline__ float softplusf(float x) {
    float e = __expf(-fabsf(x));
    return fmaxf(x, 0.f) + __logf(1.f + e);
}
__device__ __forceinline__ unsigned bf16_rne(float x) {
    unsigned u = __builtin_bit_cast(unsigned, x);
    return (u + 0x7FFFu + ((u >> 16) & 1u)) >> 16;
}
__device__ __forceinline__ float bf16f(unsigned h) {
    return __builtin_bit_cast(float, h << 16);
}
__device__ __forceinline__ int kmap(int q, int j) { return q * 8 + j; }
// Padded LDS index for kt/nt tables: 9-float4 stride per 8 entries kills the
// 4-way bank conflict of the natural stride-8 pattern (r16 counter evidence:
// conflicts 3.1M->9.96M when tables moved to LDS unpadded).
__device__ __forceinline__ int ktidx(int k) { return k + (k >> 3); }

// ws float layout:
// [0]=g0 | [16..272) kt float4[64]{w1a,w1b,b1,0} | [272..528) nt float4[64]{b2,wim2a,wim2b,w3}
// [528..2576) A1hi | [2576..4624) A1lo | [4624..6672) A2hi | [6672..8720) A2lo   (u32[2048] each)
#define WS_KT  16
#define WS_NT  272
#define WS_A1  528

__global__ void setup_kernel(const float* __restrict__ W1, const float* __restrict__ b1,
                             const float* __restrict__ W2, const float* __restrict__ b2,
                             const float* __restrict__ W3, const float* __restrict__ b3,
                             const float* __restrict__ Wim2, float* __restrict__ ws) {
    const int tid = threadIdx.x;
    float4*   kt  = (float4*)(ws + WS_KT);
    float4*   nt4 = (float4*)(ws + WS_NT);
    unsigned* A1hi = (unsigned*)(ws + WS_A1);
    unsigned* A1lo = A1hi + 2048;
    unsigned* A2hi = A1lo + 2048;
    unsigned* A2lo = A2hi + 2048;

    if (tid < 64) {
        float4 kv = make_float4(0.f, 0.f, 0.f, 0.f);
        float4 nv = make_float4(0.f, 0.f, 0.f, 0.f);
        if (tid < H) {
            kv.x = W1[2 * tid]; kv.y = W1[2 * tid + 1]; kv.z = b1[tid];
            nv.x = b2[tid]; nv.y = Wim2[2 * tid]; nv.z = Wim2[2 * tid + 1]; nv.w = W3[tid];
        }
        kt[tid] = kv; nt4[tid] = nv;
    }
    // A1 (GEMM1 A = W2):   value = W2[m][k]   (m = C-row = j, k over K)
    // A2 (GEMM2 A = W2^T): value = W2[k][m]   (m = C-row = k2, k = j)
    for (int idx = tid; idx < 2048; idx += 256) {
        const int frag = idx >> 2, rp = idx & 3;
        const int l = frag & 63, t2 = frag >> 6;
        const int kh = t2 & 1, tile = t2 >> 1;
        const int m  = tile * 16 + (l & 15);
        const int ka = kh * 32 + kmap(l >> 4, rp * 2);
        const int kb = kh * 32 + kmap(l >> 4, rp * 2 + 1);
        {
            float v0 = (ka < H && m < H) ? W2[m * H + ka] : 0.f;
            float v1 = (kb < H && m < H) ? W2[m * H + kb] : 0.f;
            unsigned h0 = bf16_rne(v0), h1 = bf16_rne(v1);
            A1hi[idx] = h0 | (h1 << 16);
            A1lo[idx] = bf16_rne(v0 - bf16f(h0)) | (bf16_rne(v1 - bf16f(h1)) << 16);
        }
        {
            float w0 = (ka < H && m < H) ? W2[ka * H + m] : 0.f;
            float w1 = (kb < H && m < H) ? W2[kb * H + m] : 0.f;
            unsigned h0 = bf16_rne(w0), h1 = bf16_rne(w1);
            A2hi[idx] = h0 | (h1 << 16);
            A2lo[idx] = bf16_rne(w0 - bf16f(h0)) | (bf16_rne(w1 - bf16f(h1)) << 16);
        }
    }
    if (tid == 0) {
        float h1v[H];
        for (int k = 0; k < H; ++k) h1v[k] = softplusf(b1[k]);
        float z3 = b3[0];
        for (int j = 0; j < H; ++j) {
            float acc = b2[j];
            for (int k = 0; k < H; ++k) acc = fmaf(W2[j * H + k], h1v[k], acc);
            z3 = fmaf(W3[j], softplusf(acc), z3);
        }
        ws[0] = softplusf(z3);
    }
}

// Swapped-operand fused kernel. Round-17 = r16 + padded sKT/sNT indexing
// (ktidx: stride 9 float4 per 8 entries) to remove the 4-way LDS bank
// conflicts on all kt/nt table reads.
__global__ __launch_bounds__(256) void fused_kernel(
    const float* __restrict__ X, const float* __restrict__ Wf,
    const float* __restrict__ Wim3, const float* __restrict__ b3,
    const float* __restrict__ ws, float* __restrict__ out, int B)
{
    __shared__ unsigned sA1hi[2048], sA1lo[2048], sA2hi[2048], sA2lo[2048]; // 32 KB
    __shared__ float4 sKT[72], sNT[72];                                     // 2.25 KB padded
    __shared__ char Traw[4][2304];   // per-wave t-tile (hi only): 16 rows x 144 B

    const int tid  = threadIdx.x;
    const int wid  = tid >> 6, lane = tid & 63;
    const int b    = lane & 15, qd = lane >> 4;
    const int rows0 = blockIdx.x * 256;

    // ---- stage tables global -> LDS (once) ----
    {
        const u32x4* gT = (const u32x4*)(ws + WS_A1);
        u32x4* s0 = (u32x4*)sA1hi; u32x4* s1 = (u32x4*)sA1lo;
        u32x4* s2 = (u32x4*)sA2hi; u32x4* s3 = (u32x4*)sA2lo;
        for (int i = tid; i < 512; i += 256) {
            s0[i] = gT[i];
            s1[i] = gT[512 + i];
            s2[i] = gT[1024 + i];
            s3[i] = gT[1536 + i];
        }
        if (tid < 64) {
            sKT[ktidx(tid)] = ((const float4*)(ws + WS_KT))[tid];
            sNT[ktidx(tid)] = ((const float4*)(ws + WS_NT))[tid];
        }
    }
    __syncthreads();

    const float g0  = ws[0];
    const float b3v = b3[0], wi30 = Wim3[0], wi31 = Wim3[1];
    const float wf0 = Wf[0], wf1 = Wf[1], wf2 = Wf[2], wf3 = Wf[3];

    char* Thi = &Traw[wid][0];

    for (int blk = 0; blk < 4; ++blk) {
        // Anti-LICM: forbid caching any table load across iterations (r14
        // lesson: LICM caches ~190 regs of tables -> 1 wave/SIMD).
        asm volatile("" ::: "memory");

        const int rloc = wid * 64 + blk * 16;
        const int row  = rows0 + rloc + b;
        const float2 xv = ((const float2*)X)[row < B ? row : 0];
        const float x0 = xv.x, x1 = xv.y;

        // ---- B1 = h1 fragments (hi + residual-lo bf16) ----
        short8 B1hi[2], B1lo[2];
#pragma unroll
        for (int kh = 0; kh < 2; ++kh) {
#pragma unroll
            for (int e = 0; e < 8; ++e) {
                const int k = kh * 32 + 8 * qd + e;
                const float4 kv = sKT[ktidx(k)];
                const float z1 = fmaf(kv.x, x0, fmaf(kv.y, x1, kv.z));
                const float h1 = softplusf(z1);
                const unsigned hi = bf16_rne(h1);
                const unsigned lo = bf16_rne(h1 - bf16f(hi));
                B1hi[kh][e] = (short)hi;
                B1lo[kh][e] = (short)lo;
            }
        }

        // ---- GEMM1: z2[j][b], split-precision 3-pass; A from LDS ----
        float4v acc[4];
#pragma unroll
        for (int jt = 0; jt < 4; ++jt) acc[jt] = (float4v){0.f, 0.f, 0.f, 0.f};
#pragma unroll
        for (int jt = 0; jt < 4; ++jt)
#pragma unroll
            for (int kh = 0; kh < 2; ++kh) {
                const int fi = ((jt * 2 + kh) * 64 + lane) * 4;
                const short8 ahi = __builtin_bit_cast(short8, *(const u32x4*)&sA1hi[fi]);
                const short8 alo = __builtin_bit_cast(short8, *(const u32x4*)&sA1lo[fi]);
                acc[jt] = __builtin_amdgcn_mfma_f32_16x16x32_bf16(ahi, B1hi[kh], acc[jt], 0, 0, 0);
                acc[jt] = __builtin_amdgcn_mfma_f32_16x16x32_bf16(alo, B1hi[kh], acc[jt], 0, 0, 0);
                acc[jt] = __builtin_amdgcn_mfma_f32_16x16x32_bf16(ahi, B1lo[kh], acc[jt], 0, 0, 0);
            }

        // ---- epilogue 1: per-lane over 16 j's; t(hi only) -> LDS tile ----
        float z3p = 0.f, gi0p = 0.f, gi1p = 0.f;
#pragma unroll
        for (int jt = 0; jt < 4; ++jt) {
            float tv[4];
#pragma unroll
            for (int c = 0; c < 4; ++c) {
                const int j = jt * 16 + 4 * qd + c;
                const float4 nv = sNT[ktidx(j)];
                const float z2 = acc[jt][c] + fmaf(nv.y, x0, fmaf(nv.z, x1, nv.x));
                const float h2 = softplusf(z2);
                z3p = fmaf(nv.w, h2, z3p);
                const float tj = nv.w * (1.f - __expf(-h2));
                gi0p = fmaf(tj, nv.y, gi0p);
                gi1p = fmaf(tj, nv.z, gi1p);
                tv[c] = tj;
            }
            u32x2 thw;
            thw.x = bf16_rne(tv[0]) | (bf16_rne(tv[1]) << 16);
            thw.y = bf16_rne(tv[2]) | (bf16_rne(tv[3]) << 16);
            *(u32x2*)(Thi + b * 144 + jt * 32 + qd * 8) = thw;
        }

        // ---- B2 = t fragments from LDS ----
        short8 B2hi[2];
#pragma unroll
        for (int kh = 0; kh < 2; ++kh)
            B2hi[kh] = *(const short8*)(Thi + b * 144 + kh * 64 + qd * 16);

        // ---- GEMM2: G[k2][b], 2-pass (A2hi+A2lo) x t-hi; A from LDS ----
        float4v gacc[4];
#pragma unroll
        for (int t = 0; t < 4; ++t) gacc[t] = (float4v){0.f, 0.f, 0.f, 0.f};
#pragma unroll
        for (int t = 0; t < 4; ++t)
#pragma unroll
            for (int kh = 0; kh < 2; ++kh) {
                const int fi = ((t * 2 + kh) * 64 + lane) * 4;
                const short8 ahi = __builtin_bit_cast(short8, *(const u32x4*)&sA2hi[fi]);
                const short8 alo = __builtin_bit_cast(short8, *(const u32x4*)&sA2lo[fi]);
                gacc[t] = __builtin_amdgcn_mfma_f32_16x16x32_bf16(ahi, B2hi[kh], gacc[t], 0, 0, 0);
                gacc[t] = __builtin_amdgcn_mfma_f32_16x16x32_bf16(alo, B2hi[kh], gacc[t], 0, 0, 0);
            }

        // ---- epilogue 2: per-lane over 16 k2's ----
        float q0p = 0.f, q1p = 0.f;
#pragma unroll
        for (int t = 0; t < 4; ++t)
#pragma unroll
            for (int c = 0; c < 4; ++c) {
                const int k2 = t * 16 + 4 * qd + c;
                const float4 kv = sKT[ktidx(k2)];
                const float z1 = fmaf(kv.x, x0, fmaf(kv.y, x1, kv.z));
                const float sg = __fdividef(1.f, 1.f + __expf(-z1));
                const float u1 = gacc[t][c] * sg;
                q0p = fmaf(u1, kv.x, q0p);
                q1p = fmaf(u1, kv.y, q1p);
            }

        // ---- qd-group reductions: 2 shuffle steps each ----
        z3p  += __shfl_xor(z3p, 16);  z3p  += __shfl_xor(z3p, 32);
        gi0p += __shfl_xor(gi0p, 16); gi0p += __shfl_xor(gi0p, 32);
        gi1p += __shfl_xor(gi1p, 16); gi1p += __shfl_xor(gi1p, 32);
        q0p  += __shfl_xor(q0p, 16);  q0p  += __shfl_xor(q0p, 32);
        q1p  += __shfl_xor(q1p, 16);  q1p  += __shfl_xor(q1p, 32);

        // ---- final per-row scalar math + store (qd==0 lanes) ----
        const float z3 = z3p + fmaf(wi30, x0, fmaf(wi31, x1, b3v));
        const float g  = softplusf(z3);
        const float u3 = (g > g0) ? (1.f - __expf(-g)) : 0.f;
        const float dv0 = fmaf(2.f * EPS, x0, u3 * (wi30 + gi0p + q0p));
        const float dv1 = fmaf(2.f * EPS, x1, u3 * (wi31 + gi1p + q1p));
        const float V  = fmaxf(g - g0, 0.f) + EPS * fmaf(x0, x0, x1 * x1);
        const float f0 = fmaf(wf0, x0, wf1 * x1);
        const float f1 = fmaf(wf2, x0, wf3 * x1);
        const float stab = fmaf(ALPHA, V, fmaf(dv0, f0, dv1 * f1));
        const float s = __fdividef(fmaxf(stab, 0.f), fmaf(dv0, dv0, dv1 * dv1));
        if (qd == 0 && row < B)
            ((float2*)out)[row] = make_float2(f0 - dv0 * s, f1 - dv1 * s);
    }
}

// ---- fallback (monolithic scalar) if ws is too small ----
__global__ void g0_kernel(const float* __restrict__ W2, const float* __restrict__ b1,
                          const float* __restrict__ b2, const float* __restrict__ W3,
                          const float* __restrict__ b3, float* __restrict__ g0_out) {
    if (threadIdx.x != 0 || blockIdx.x != 0) return;
    float h1[H];
    for (int k = 0; k < H; ++k) h1[k] = softplusf(b1[k]);
    float z3 = b3[0];
    for (int j = 0; j < H; ++j) {
        float acc = b2[j];
        for (int k = 0; k < H; ++k) acc = fmaf(W2[j * H + k], h1[k], acc);
        z3 = fmaf(W3[j], softplusf(acc), z3);
    }
    g0_out[0] = softplusf(z3);
}

__global__ __launch_bounds__(256) void sdnn_mono_kernel(
    const float* __restrict__ X,   const float* __restrict__ Wf,
    const float* __restrict__ W1,  const float* __restrict__ b1,
    const float* __restrict__ W2,  const float* __restrict__ b2,
    const float* __restrict__ W3,  const float* __restrict__ b3,
    const float* __restrict__ Wim2,const float* __restrict__ Wim3,
    const float* __restrict__ g0p, float* __restrict__ out, int B)
{
    const int row = blockIdx.x * 256 + threadIdx.x;
    if (row >= B) return;
    const float2 xv = ((const float2*)X)[row];
    const float x0 = xv.x, x1 = xv.y;
    float h1v[H];
#pragma unroll
    for (int k = 0; k < H; ++k)
        h1v[k] = softplusf(fmaf(W1[2 * k], x0, fmaf(W1[2 * k + 1], x1, b1[k])));
    float G[H];
#pragma unroll
    for (int k = 0; k < H; ++k) G[k] = 0.f;
    const float wi30 = Wim3[0], wi31 = Wim3[1];
    float z3 = fmaf(wi30, x0, fmaf(wi31, x1, b3[0]));
    float gim0 = 0.f, gim1 = 0.f;
    for (int j = 0; j < H; ++j) {
        const float* __restrict__ wrow = &W2[j * H];
        float a0 = 0.f, a1 = 0.f, a2 = 0.f, a3 = 0.f;
#pragma unroll
        for (int k = 0; k < H; k += 4) {
            a0 = fmaf(wrow[k + 0], h1v[k + 0], a0);
            a1 = fmaf(wrow[k + 1], h1v[k + 1], a1);
            a2 = fmaf(wrow[k + 2], h1v[k + 2], a2);
            a3 = fmaf(wrow[k + 3], h1v[k + 3], a3);
        }
        float acc = ((a0 + a1) + (a2 + a3))
                  + fmaf(Wim2[2 * j], x0, fmaf(Wim2[2 * j + 1], x1, b2[j]));
        const float h2  = softplusf(acc);
        const float w3j = W3[j];
        z3 = fmaf(w3j, h2, z3);
        const float tj = w3j * (1.f - __expf(-h2));
        gim0 = fmaf(tj, Wim2[2 * j],     gim0);
        gim1 = fmaf(tj, Wim2[2 * j + 1], gim1);
#pragma unroll
        for (int k = 0; k < H; ++k) G[k] = fmaf(wrow[k], tj, G[k]);
    }
    const float g0 = g0p[0];
    const float g  = softplusf(z3);
    const float u3 = (g > g0) ? (1.f - __expf(-g)) : 0.f;
    float q0 = 0.f, q1 = 0.f;
#pragma unroll
    for (int k = 0; k < H; ++k) {
        const float u1 = G[k] * (1.f - __expf(-h1v[k]));
        q0 = fmaf(u1, W1[2 * k],     q0);
        q1 = fmaf(u1, W1[2 * k + 1], q1);
    }
    const float dV0 = fmaf(2.f * EPS, x0, u3 * (wi30 + gim0 + q0));
    const float dV1 = fmaf(2.f * EPS, x1, u3 * (wi31 + gim1 + q1));
    const float V  = fmaxf(g - g0, 0.f) + EPS * fmaf(x0, x0, x1 * x1);
    const float f0 = fmaf(Wf[0], x0, Wf[1] * x1);
    const float f1 = fmaf(Wf[2], x0, Wf[3] * x1);
    const float stab = fmaf(ALPHA, V, fmaf(dV0, f0, dV1 * f1));
    const float s    = __fdividef(fmaxf(stab, 0.f), fmaf(dV0, dV0, dV1 * dV1));
    float2 o;
    o.x = f0 - dV0 * s;
    o.y = f1 - dV1 * s;
    ((float2*)out)[row] = o;
}

extern "C" void kernel_launch(void* const* d_in, const int* in_sizes, int n_in,
                              void* d_out, int out_size, void* d_ws, size_t ws_size,
                              hipStream_t stream) {
    const float* X    = (const float*)d_in[0];
    const float* Wf   = (const float*)d_in[1];
    const float* W1   = (const float*)d_in[2];
    const float* b1   = (const float*)d_in[3];
    const float* W2   = (const float*)d_in[4];
    const float* b2   = (const float*)d_in[5];
    const float* W3   = (const float*)d_in[6];
    const float* b3   = (const float*)d_in[7];
    const float* Wim2 = (const float*)d_in[8];
    const float* Wim3 = (const float*)d_in[9];
    float* out = (float*)d_out;
    float* wsf = (float*)d_ws;

    const int B = in_sizes[0] / 2;
    const int nwg = (B + 255) / 256;

    if (ws_size >= 8720u * 4u) {
        hipLaunchKernelGGL(setup_kernel, dim3(1), dim3(256), 0, stream,
                           W1, b1, W2, b2, W3, b3, Wim2, wsf);
        hipLaunchKernelGGL(fused_kernel, dim3(nwg), dim3(256), 0, stream,
                           X, Wf, Wim3, b3, wsf, out, B);
    } else {
        hipLaunchKernelGGL(g0_kernel, dim3(1), dim3(64), 0, stream,
                           W2, b1, b2, W3, b3, wsf);
        hipLaunchKernelGGL(sdnn_mono_kernel, dim3(nwg), dim3(256), 0, stream,
                           X, Wf, W1, b1, W2, b2, W3, b3, Wim2, Wim3, wsf, out, B);
    }
}